// Round 3
// baseline (352.968 us; speedup 1.0000x reference)
//
#include <hip/hip_runtime.h>

typedef float f32x4 __attribute__((ext_vector_type(4)));
typedef __bf16 bf16x8 __attribute__((ext_vector_type(8)));
typedef unsigned short u16x8 __attribute__((ext_vector_type(8)));

__device__ __forceinline__ unsigned short f2bf(float f) {
  union { float f; unsigned int u; } v; v.f = f;
  unsigned int u = v.u;
  unsigned int r = (u + 0x7FFFu + ((u >> 16) & 1u)) >> 16;  // RNE
  return (unsigned short)r;
}

// ---------------- cast x (f32 -> bf16), 8 elems/thread ----------------
__global__ void k_cast_bf16(const float* __restrict__ in,
                            unsigned short* __restrict__ out, int n8) {
  int i = blockIdx.x * blockDim.x + threadIdx.x;
  if (i >= n8) return;
  const f32x4* p = (const f32x4*)in;
  f32x4 a = p[2 * i], b = p[2 * i + 1];
  u16x8 o;
  o[0] = f2bf(a[0]); o[1] = f2bf(a[1]); o[2] = f2bf(a[2]); o[3] = f2bf(a[3]);
  o[4] = f2bf(b[0]); o[5] = f2bf(b[1]); o[6] = f2bf(b[2]); o[7] = f2bf(b[3]);
  ((u16x8*)out)[i] = o;
}

// -------- Bw[o][e*16+r] = coeffs[e]*scales[e]*Bf[e][o][r], bf16 --------
__global__ void k_build_bw(const float* __restrict__ Bf,
                           const float* __restrict__ coeffs,
                           const float* __restrict__ scales,
                           unsigned short* __restrict__ bw) {
  int t = blockIdx.x * 256 + threadIdx.x;
  int o = t >> 8, k = t & 255, e = k >> 4, r = k & 15;
  float v = coeffs[e] * scales[e] * Bf[((size_t)e * 4096 + o) * 16 + r];
  bw[t] = f2bf(v);
}

// -------- At[d][e*16+r] = A[e][r][d], bf16, via LDS transpose --------
__global__ void k_build_at(const float* __restrict__ A,
                           unsigned short* __restrict__ at) {
  __shared__ float tile[64][65];
  int kt = blockIdx.x * 64, dt = blockIdx.y * 64;
  int tx = threadIdx.x & 63, ty = threadIdx.x >> 6;
#pragma unroll
  for (int j = 0; j < 64; j += 4)
    tile[ty + j][tx] = A[(size_t)(kt + ty + j) * 4096 + dt + tx];
  __syncthreads();
#pragma unroll
  for (int j = 0; j < 64; j += 4)
    at[(size_t)(dt + ty + j) * 256 + kt + tx] = f2bf(tile[tx][ty + j]);
}

// ------------- prep GEMM (m97 structure), W_eff = Bw @ At^T + W -------------
template <int M_, int N_, int K_>
__global__ __launch_bounds__(256) void k_gemm_prep(
    const unsigned short* __restrict__ Abuf,
    const unsigned short* __restrict__ Bbuf,
    const float* __restrict__ Wadd,
    unsigned short* __restrict__ outB) {
  constexpr int NBN = N_ / 128;
  constexpr int NWG = (M_ / 128) * NBN;
  const int bid = blockIdx.x;
  const int swz = (bid & 7) * (NWG / 8) + (bid >> 3);
  const int bm = swz / NBN, bn = swz % NBN;

  __shared__ unsigned short ldsA[128 * 64];
  __shared__ unsigned short ldsB[128 * 64];

  const int t = threadIdx.x, w = t >> 6, l = t & 63;
  const int wr = w >> 1, wc = w & 1;

  f32x4 acc[4][4] = {};
  const int m0 = bm * 128, n0 = bn * 128;
  const int srow = w * 8 + (l >> 3);
  const int scol = (l & 7) * 8;
  const unsigned short* gA = Abuf + (size_t)(m0 + srow) * K_ + scol;
  const unsigned short* gB = Bbuf + (size_t)(n0 + srow) * K_ + scol;

  for (int kt = 0; kt < K_; kt += 64) {
#pragma unroll
    for (int i = 0; i < 4; ++i) {
      __builtin_amdgcn_global_load_lds(
          (__attribute__((address_space(1))) void*)(gA + (size_t)i * 32 * K_ + kt),
          (__attribute__((address_space(3))) void*)(ldsA + i * 2048 + w * 512), 16, 0, 0);
      __builtin_amdgcn_global_load_lds(
          (__attribute__((address_space(1))) void*)(gB + (size_t)i * 32 * K_ + kt),
          (__attribute__((address_space(3))) void*)(ldsB + i * 2048 + w * 512), 16, 0, 0);
    }
    __syncthreads();
#pragma unroll
    for (int kk = 0; kk < 2; ++kk) {
      const int col = kk * 32 + (l >> 4) * 8;
      const int arow = wr * 64 + (l & 15);
      const int brow = wc * 64 + (l & 15);
      bf16x8 af[4], bfv[4];
#pragma unroll
      for (int mi = 0; mi < 4; ++mi)
        af[mi] = *(const bf16x8*)&ldsA[(arow + mi * 16) * 64 + col];
#pragma unroll
      for (int ni = 0; ni < 4; ++ni)
        bfv[ni] = *(const bf16x8*)&ldsB[(brow + ni * 16) * 64 + col];
#pragma unroll
      for (int mi = 0; mi < 4; ++mi)
#pragma unroll
        for (int ni = 0; ni < 4; ++ni)
          acc[mi][ni] = __builtin_amdgcn_mfma_f32_16x16x32_bf16(
              af[mi], bfv[ni], acc[mi][ni], 0, 0, 0);
    }
    __syncthreads();
  }

  const int mrow0 = m0 + wr * 64 + (l >> 4) * 4;
  const int ncol0 = n0 + wc * 64 + (l & 15);
#pragma unroll
  for (int mi = 0; mi < 4; ++mi)
#pragma unroll
    for (int r = 0; r < 4; ++r) {
      const int m = mrow0 + mi * 16 + r;
#pragma unroll
      for (int ni = 0; ni < 4; ++ni) {
        const int n = ncol0 + ni * 16;
        outB[(size_t)m * N_ + n] = f2bf(acc[mi][ni][r] + Wadd[(size_t)m * N_ + n]);
      }
    }
}

// ============ main GEMM: 256x256 tile, BK=32, 4-buf deep pipeline ============
// A [M_][K_] bf16, B [N_][K_] bf16, out f32 = A*B^T + bias.
// LDS 128 KiB = 4 bufs x 32 KiB (A [256][32] at +0, B at +16384).
// Rows are 64 B (4 x 16B blocks). XOR swizzle: phys block = q ^ ((row>>1)&3);
// staging keeps LDS dest linear, pre-swizzles the GLOBAL source (rule #21):
// lane l fetches global block (l&3) ^ ((l>>3)&3).
// Pipeline: stage runs 3 tiles ahead; per tile: vmcnt(8) -> s_barrier ->
// 12 ds_read_b128 -> stage t+3 -> setprio(1) -> 32 MFMA -> setprio(0).
template <int M_, int N_, int K_>
__global__ __launch_bounds__(512, 2) void k_gemm256(
    const unsigned short* __restrict__ Abuf,
    const unsigned short* __restrict__ Bbuf,
    const float* __restrict__ bias,
    float* __restrict__ outF) {
  constexpr int NBN = N_ / 256;
  constexpr int NWG = (M_ / 256) * NBN;
  constexpr int NT = K_ / 32;
  static_assert(NWG % 8 == 0, "bijective xcd swizzle");
  static_assert(NT >= 4, "pipeline depth");

  const int bid = blockIdx.x;
  const int swz = (bid & 7) * (NWG / 8) + (bid >> 3);
  const int bm = swz / NBN, bn = swz % NBN;
  const int m0 = bm * 256, n0 = bn * 256;

  __shared__ __attribute__((aligned(128))) unsigned short lds[65536];  // 128 KiB
  char* ldsb = (char*)lds;

  const int tid = threadIdx.x, w = tid >> 6, l = tid & 63;
  const int wr = w >> 2, wc = w & 3;  // 2 M-waves x 4 N-waves; per-wave 128x64

  // staging: wave w, instr i (0,1) covers rows i*128 + w*16 .. +15 (of A and B).
  // lane l -> row += l>>2, phys 16B block = l&3 (linear dest);
  // global source block pre-swizzled: (l&3) ^ ((l>>3)&3).
  const int scol = ((l & 3) ^ ((l >> 3) & 3)) * 8;
  const unsigned short* gA = Abuf + (size_t)(m0 + w * 16 + (l >> 2)) * K_ + scol;
  const unsigned short* gB = Bbuf + (size_t)(n0 + w * 16 + (l >> 2)) * K_ + scol;
  const int dA = w * 1024;            // + buf*32768 + i*8192
  const int dB = 16384 + w * 1024;

  // fragment reads: row = base + (l&15), q = l>>4; phys block = q ^ ((row>>1)&3)
  const int qp = ((l >> 4) ^ ((l >> 1) & 3)) * 16;
  const int raOff = (wr * 128 + (l & 15)) * 64 + qp;           // + mi*1024
  const int rbOff = 16384 + (wc * 64 + (l & 15)) * 64 + qp;    // + ni*1024

  f32x4 acc[8][4] = {};

#define STAGE_T(tt)                                                               \
  do {                                                                            \
    const int bb0_ = ((tt) & 3) << 15;                                            \
    const size_t ko_ = (size_t)(tt) * 32;                                         \
    _Pragma("unroll") for (int i_ = 0; i_ < 2; ++i_) {                            \
      __builtin_amdgcn_global_load_lds(                                           \
          (__attribute__((address_space(1))) void*)(gA + (size_t)i_ * 128 * K_ + ko_), \
          (__attribute__((address_space(3))) void*)(ldsb + bb0_ + i_ * 8192 + dA),     \
          16, 0, 0);                                                              \
      __builtin_amdgcn_global_load_lds(                                           \
          (__attribute__((address_space(1))) void*)(gB + (size_t)i_ * 128 * K_ + ko_), \
          (__attribute__((address_space(3))) void*)(ldsb + bb0_ + i_ * 8192 + dB),     \
          16, 0, 0);                                                              \
    }                                                                             \
  } while (0)

  // prologue: stage tiles 0,1,2 (12 loads/wave in flight)
  STAGE_T(0); STAGE_T(1); STAGE_T(2);

  for (int t = 0; t < NT; ++t) {
    // drain exactly tile t's 4 loads (t+1, t+2 stay in flight)
    if (t + 2 < NT)      asm volatile("s_waitcnt vmcnt(8)" ::: "memory");
    else if (t + 1 < NT) asm volatile("s_waitcnt vmcnt(4)" ::: "memory");
    else                 asm volatile("s_waitcnt vmcnt(0)" ::: "memory");
    __builtin_amdgcn_s_barrier();  // raw barrier: no vmcnt(0) drain

    const int bb0 = (t & 3) << 15;
    bf16x8 af[8], bv[4];
#pragma unroll
    for (int mi = 0; mi < 8; ++mi)
      af[mi] = *(const bf16x8*)(ldsb + bb0 + raOff + mi * 1024);
#pragma unroll
    for (int ni = 0; ni < 4; ++ni)
      bv[ni] = *(const bf16x8*)(ldsb + bb0 + rbOff + ni * 1024);

    if (t + 3 < NT) STAGE_T(t + 3);  // writes buf (t-1)&3: freed by this barrier

    __builtin_amdgcn_s_setprio(1);
#pragma unroll
    for (int mi = 0; mi < 8; ++mi)
#pragma unroll
      for (int ni = 0; ni < 4; ++ni)
        acc[mi][ni] = __builtin_amdgcn_mfma_f32_16x16x32_bf16(
            af[mi], bv[ni], acc[mi][ni], 0, 0, 0);
    __builtin_amdgcn_s_setprio(0);
  }
#undef STAGE_T

  // epilogue: C/D layout col = lane&15, row = (lane>>4)*4 + reg
#pragma unroll
  for (int ni = 0; ni < 4; ++ni) {
    const int n = n0 + wc * 64 + ni * 16 + (l & 15);
    const float bv2 = bias[n];
#pragma unroll
    for (int mi = 0; mi < 8; ++mi) {
      const int m = m0 + wr * 128 + mi * 16 + (l >> 4) * 4;
#pragma unroll
      for (int r = 0; r < 4; ++r)
        outF[(size_t)(m + r) * N_ + n] = acc[mi][ni][r] + bv2;
    }
  }
}

extern "C" void kernel_launch(void* const* d_in, const int* in_sizes, int n_in,
                              void* d_out, int out_size, void* d_ws, size_t ws_size,
                              hipStream_t stream) {
  const float* x      = (const float*)d_in[0];
  const float* W      = (const float*)d_in[1];
  const float* bias   = (const float*)d_in[2];
  const float* A      = (const float*)d_in[3];
  const float* Bf     = (const float*)d_in[4];
  const float* coeffs = (const float*)d_in[5];
  const float* scales = (const float*)d_in[6];
  float* out = (float*)d_out;

  char* ws = (char*)d_ws;
  unsigned short* xb   = (unsigned short*)(ws);
  unsigned short* weff = (unsigned short*)(ws + 67108864);
  unsigned short* bw   = (unsigned short*)(ws + 67108864 + 33554432);
  unsigned short* at   = (unsigned short*)(ws + 67108864 + 33554432 + 2097152);

  k_cast_bf16<<<16384, 256, 0, stream>>>(x, xb, (8192 * 4096) / 8);
  k_build_bw<<<4096, 256, 0, stream>>>(Bf, coeffs, scales, bw);
  k_build_at<<<dim3(4, 64), 256, 0, stream>>>(A, at);
  k_gemm_prep<4096, 4096, 256><<<1024, 256, 0, stream>>>(bw, at, W, weff);
  k_gemm256<8192, 4096, 4096><<<512, 512, 0, stream>>>(xb, weff, bias, out);
}